// Round 7
// baseline (220.003 us; speedup 1.0000x reference)
//
#include <hip/hip_runtime.h>

static inline int ceil_div(long long a, long long b) { return (int)((a + b - 1) / b); }

// Node-range binning: bin = dst >> 8 (256 nodes per bin). N <= 131072 assumed (N=100000).
#define RBITS 8
#define RNODES 256
#define CAPB 12
#define CAP 4096   // slots per bin; E/NB ~= 3070, Poisson sigma ~55 -> 4096 is 18-sigma safe

typedef __attribute__((ext_vector_type(8))) short bf16x8;
typedef __attribute__((ext_vector_type(4))) float f32x4;
typedef __attribute__((ext_vector_type(2))) unsigned u32x2;
typedef __attribute__((ext_vector_type(4))) unsigned u32x4;

// bf16 helpers: pack with round-to-nearest-even, unpack via bit ops
__device__ inline unsigned f2bf(float f) {
    unsigned u = __float_as_uint(f);
    return (u + 0x7fffu + ((u >> 16) & 1u)) >> 16;
}
__device__ inline unsigned pack2(float a, float b) { return f2bf(a) | (f2bf(b) << 16); }
__device__ inline float bf2f(unsigned v) { return __uint_as_float(v << 16); }
__device__ inline float bf_lo(unsigned v) { return __uint_as_float(v << 16); }
__device__ inline float bf_hi(unsigned v) { return __uint_as_float(v & 0xffff0000u); }

// ---------------- step 1: partition edges into capped bin regions (LDS staging) ----------------
// bin b owns slots [b*CAP, b*CAP + len_b); bin_cursor[b] ends up = len_b.
// SC_E=2048 -> 586 blocks (~2.3/CU) so the 18 barriers/block overlap across blocks.
#define SC_T 512
#define SC_K 4
#define SC_E (SC_T * SC_K)   // 2048 edges per block
__global__ void bin_scatter(const int* __restrict__ src, const int* __restrict__ dst,
                            const float* __restrict__ w, int* __restrict__ bin_cursor,
                            int* __restrict__ bp, float* __restrict__ bw,
                            int NB, int E) {
    __shared__ int hist[512];
    __shared__ int offs[512];               // inclusive scan of hist
    __shared__ int basex[512];              // global write base per bin
    __shared__ int stage_p[SC_E];
    __shared__ float stage_w[SC_E];
    __shared__ unsigned short stage_b[SC_E]; // bin id per staged slot
    int t = threadIdx.x;
    hist[t] = 0;
    __syncthreads();
    int e0 = blockIdx.x * SC_E;
    int nE = E - e0; if (nE > SC_E) nE = SC_E;

    int myBin[SC_K], myRank[SC_K], myPack[SC_K];
    float myW[SC_K];
#pragma unroll
    for (int k = 0; k < SC_K; ++k) {
        int idx = t + k * SC_T;
        if (idx < nE) {
            int e = e0 + idx;
            int d = dst[e];
            int b = d >> RBITS;
            myBin[k] = b;
            myPack[k] = (src[e] << RBITS) | (d & (RNODES - 1));
            myW[k] = w[e];
            myRank[k] = atomicAdd(&hist[b], 1);
        }
    }
    __syncthreads();
    offs[t] = hist[t];
    __syncthreads();
    for (int d = 1; d < 512; d <<= 1) {
        int a = (t >= d) ? offs[t - d] : 0;
        __syncthreads();
        offs[t] += a;
        __syncthreads();
    }
    if (t < NB && hist[t]) basex[t] = (t << CAPB) + atomicAdd(&bin_cursor[t], hist[t]);
#pragma unroll
    for (int k = 0; k < SC_K; ++k) {
        int idx = t + k * SC_T;
        if (idx < nE) {
            int b = myBin[k];
            int pos = (offs[b] - hist[b]) + myRank[k];
            stage_p[pos] = myPack[k];
            stage_w[pos] = myW[k];
            stage_b[pos] = (unsigned short)b;
        }
    }
    __syncthreads();
    for (int p = t; p < nE; p += SC_T) {
        int b = stage_b[p];
        int g = basex[b] + (p - (offs[b] - hist[b]));
        bp[g] = stage_p[p];
        bw[g] = stage_w[p];
    }
}

// ---------------- step 2: fused degree + CSR scatter (proven round 2/6; wsum output) -------
// row_rc packs (cnt<<21)|pos  (pos < 2^21, cnt < 2^11).
__global__ void build_csr(const int* __restrict__ bp, const float* __restrict__ bw,
                          const int* __restrict__ bin_len,
                          unsigned* __restrict__ row_rc, float* __restrict__ wsum_g,
                          u32x2* __restrict__ ew, int N) {
    __shared__ int bp_s[CAP];
    __shared__ float bw_s[CAP];
    __shared__ int cnt[RNODES];
    __shared__ float wsum[RNODES];
    __shared__ int starts[RNODES];
    __shared__ int cur[RNODES];
    int b = blockIdx.x;
    int t = threadIdx.x;   // 512
    int len = bin_len[b];
    int base = b << CAPB;
    if (t < RNODES) { cnt[t] = 0; wsum[t] = 0.f; }
    __syncthreads();
    for (int e = t; e < len; e += 512) {
        int p = bp[base + e];
        float wv = bw[base + e];
        bp_s[e] = p;
        bw_s[e] = wv;
        atomicAdd(&cnt[p & (RNODES - 1)], 1);
        atomicAdd(&wsum[p & (RNODES - 1)], wv);
    }
    __syncthreads();
    if (t < RNODES) starts[t] = cnt[t];
    __syncthreads();
    for (int d = 1; d < RNODES; d <<= 1) {
        int a = 0;
        if (t < RNODES && t >= d) a = starts[t - d];
        __syncthreads();
        if (t < RNODES) starts[t] += a;
        __syncthreads();
    }
    if (t < RNODES) {
        int s0 = starts[t] - cnt[t];
        cur[t] = s0;
        int node = (b << RBITS) + t;
        if (node < N) {
            row_rc[node] = (unsigned)(base + s0) | ((unsigned)cnt[t] << 21);
            wsum_g[node] = wsum[t];
        }
    }
    __syncthreads();
    for (int e = t; e < len; e += 512) {
        int p = bp_s[e];
        int slot = atomicAdd(&cur[p & (RNODES - 1)], 1);
        u32x2 v;
        v.x = (unsigned)(p >> RBITS);
        v.y = __float_as_uint(bw_s[e]);
        ew[base + slot] = v;
    }
}

// ---------------- MFMA GEMMs (dinv = rsqrt(wsum+1) folded into epilogue; verified r4-r6) -----
__global__ __launch_bounds__(256) void gemm1_mfma(const float* __restrict__ X,
                                                  const float* __restrict__ W,
                                                  const float* __restrict__ wsum,
                                                  unsigned short* __restrict__ H, int N) {
    int lane = threadIdx.x & 63;
    int wv = threadIdx.x >> 6;
    int quad = lane >> 4;
    int col = lane & 15;
    int rb = blockIdx.x * 64 + wv * 16;
    if (rb >= N) return;                      // wave-uniform

    bf16x8 Bh[4][2], Bl[4][2];
#pragma unroll
    for (int nt = 0; nt < 4; ++nt)
#pragma unroll
        for (int kh = 0; kh < 2; ++kh)
#pragma unroll
            for (int j = 0; j < 8; ++j) {
                float wval = W[(kh * 32 + quad * 8 + j) * 64 + nt * 16 + col];
                unsigned hb = f2bf(wval);
                Bh[nt][kh][j] = (short)hb;
                Bl[nt][kh][j] = (short)f2bf(wval - bf2f(hb));
            }

    int arow = rb + col;
    bf16x8 Ah[2], Al[2];
#pragma unroll
    for (int kh = 0; kh < 2; ++kh) {
        float xv[8];
        if (arow < N) {
            const float4* p = (const float4*)(X + (size_t)arow * 64 + kh * 32 + quad * 8);
            float4 f0 = p[0], f1 = p[1];
            xv[0] = f0.x; xv[1] = f0.y; xv[2] = f0.z; xv[3] = f0.w;
            xv[4] = f1.x; xv[5] = f1.y; xv[6] = f1.z; xv[7] = f1.w;
        } else {
#pragma unroll
            for (int j = 0; j < 8; ++j) xv[j] = 0.f;
        }
#pragma unroll
        for (int j = 0; j < 8; ++j) {
            unsigned hb = f2bf(xv[j]);
            Ah[kh][j] = (short)hb;
            Al[kh][j] = (short)f2bf(xv[j] - bf2f(hb));
        }
    }
    f32x4 acc[4] = {{0,0,0,0},{0,0,0,0},{0,0,0,0},{0,0,0,0}};
#pragma unroll
    for (int nt = 0; nt < 4; ++nt)
#pragma unroll
        for (int kh = 0; kh < 2; ++kh) {
            acc[nt] = __builtin_amdgcn_mfma_f32_16x16x32_bf16(Ah[kh], Bh[nt][kh], acc[nt], 0, 0, 0);
            acc[nt] = __builtin_amdgcn_mfma_f32_16x16x32_bf16(Al[kh], Bh[nt][kh], acc[nt], 0, 0, 0);
            acc[nt] = __builtin_amdgcn_mfma_f32_16x16x32_bf16(Ah[kh], Bl[nt][kh], acc[nt], 0, 0, 0);
        }
    float di[4];
#pragma unroll
    for (int r = 0; r < 4; ++r) {
        int row = rb + quad * 4 + r;
        di[r] = (row < N) ? rsqrtf(wsum[row] + 1.0f) : 0.f;
    }
#pragma unroll
    for (int nt = 0; nt < 4; ++nt)
#pragma unroll
        for (int r = 0; r < 4; ++r) {
            int row = rb + quad * 4 + r;
            if (row < N)
                H[(size_t)row * 64 + nt * 16 + col] = (unsigned short)f2bf(di[r] * acc[nt][r]);
        }
}

__global__ __launch_bounds__(256) void gemm2_mfma(const unsigned short* __restrict__ Xb,
                                                  const float* __restrict__ W,
                                                  const float* __restrict__ wsum,
                                                  unsigned short* __restrict__ H, int N) {
    int lane = threadIdx.x & 63;
    int wv = threadIdx.x >> 6;
    int quad = lane >> 4;
    int col = lane & 15;
    int rb = blockIdx.x * 64 + wv * 16;
    if (rb >= N) return;

    bf16x8 Bh[2][2], Bl[2][2];
#pragma unroll
    for (int nt = 0; nt < 2; ++nt)
#pragma unroll
        for (int kh = 0; kh < 2; ++kh)
#pragma unroll
            for (int j = 0; j < 8; ++j) {
                float wval = W[(kh * 32 + quad * 8 + j) * 32 + nt * 16 + col];
                unsigned hb = f2bf(wval);
                Bh[nt][kh][j] = (short)hb;
                Bl[nt][kh][j] = (short)f2bf(wval - bf2f(hb));
            }

    int arow = rb + col;
    bf16x8 A[2];
#pragma unroll
    for (int kh = 0; kh < 2; ++kh) {
        if (arow < N) {
            const bf16x8* p = (const bf16x8*)(Xb + (size_t)arow * 64 + kh * 32 + quad * 8);
            A[kh] = *p;                        // already bf16 — exact
        } else {
            A[kh] = bf16x8{0,0,0,0,0,0,0,0};
        }
    }
    f32x4 acc[2] = {{0,0,0,0},{0,0,0,0}};
#pragma unroll
    for (int nt = 0; nt < 2; ++nt)
#pragma unroll
        for (int kh = 0; kh < 2; ++kh) {
            acc[nt] = __builtin_amdgcn_mfma_f32_16x16x32_bf16(A[kh], Bh[nt][kh], acc[nt], 0, 0, 0);
            acc[nt] = __builtin_amdgcn_mfma_f32_16x16x32_bf16(A[kh], Bl[nt][kh], acc[nt], 0, 0, 0);
        }
    float di[4];
#pragma unroll
    for (int r = 0; r < 4; ++r) {
        int row = rb + quad * 4 + r;
        di[r] = (row < N) ? rsqrtf(wsum[row] + 1.0f) : 0.f;
    }
#pragma unroll
    for (int nt = 0; nt < 2; ++nt)
#pragma unroll
        for (int r = 0; r < 4; ++r) {
            int row = rb + quad * 4 + r;
            if (row < N)
                H[(size_t)row * 32 + nt * 16 + col] = (unsigned short)f2bf(di[r] * acc[nt][r]);
        }
}

// ---------------- aggregation: 32 lanes/node = 4 teams x 8 ch-lanes, 2-phase batched MLP ----
// Phase 1: up to 8 independent ew loads. Phase 2: up to 8 independent 16B gathers.
// Dependent-chain per node = 2 memory rounds (was ~1+deg/4).
__global__ __launch_bounds__(512) void aggregate64(const unsigned* __restrict__ h,
                            const unsigned* __restrict__ row_rc,
                            const u32x2* __restrict__ ew, const float* __restrict__ wsum,
                            const float* __restrict__ b, unsigned* __restrict__ outb, int N) {
    int t = threadIdx.x;
    int c = t & 7;                        // uint4 index in row (8 ch per lane)
    int team = (t >> 3) & 3;              // 4 edge teams
    int i = blockIdx.x * 16 + (t >> 5);   // node per 32-lane group
    if (i >= N) return;
    unsigned rc = row_rc[i];
    int beg = (int)(rc & 0x1FFFFFu);
    int len = (int)(rc >> 21);
    int q = len >> 2, r = len & 3;
    int myCnt = q + (team < r ? 1 : 0);
    int myBeg = beg + team * q + (team < r ? team : r);
    const uint4* h4 = (const uint4*)h;
    int m = myCnt < 8 ? myCnt : 8;        // covers row deg <= 32 (a.s. for Poisson(12))
    u32x2 ee[8];
#pragma unroll
    for (int j = 0; j < 8; ++j) if (j < m) ee[j] = ew[myBeg + j];
    uint4 vv[8];
#pragma unroll
    for (int j = 0; j < 8; ++j) if (j < m) vv[j] = h4[(size_t)ee[j].x * 8 + c];
    float acc[8];
#pragma unroll
    for (int j = 0; j < 8; ++j) acc[j] = 0.f;
#pragma unroll
    for (int j = 0; j < 8; ++j) if (j < m) {
        float n = __uint_as_float(ee[j].y);
        acc[0] += n * bf_lo(vv[j].x);
        acc[1] += n * bf_hi(vv[j].x);
        acc[2] += n * bf_lo(vv[j].y);
        acc[3] += n * bf_hi(vv[j].y);
        acc[4] += n * bf_lo(vv[j].z);
        acc[5] += n * bf_hi(vv[j].z);
        acc[6] += n * bf_lo(vv[j].w);
        acc[7] += n * bf_hi(vv[j].w);
    }
    for (int k = 8; k < myCnt; ++k) {     // rare tail (row deg > 32)
        u32x2 e0 = ew[myBeg + k];
        float n0 = __uint_as_float(e0.y);
        uint4 v0 = h4[(size_t)e0.x * 8 + c];
        acc[0] += n0 * bf_lo(v0.x);
        acc[1] += n0 * bf_hi(v0.x);
        acc[2] += n0 * bf_lo(v0.y);
        acc[3] += n0 * bf_hi(v0.y);
        acc[4] += n0 * bf_lo(v0.z);
        acc[5] += n0 * bf_hi(v0.z);
        acc[6] += n0 * bf_lo(v0.w);
        acc[7] += n0 * bf_hi(v0.w);
    }
    // cross-team reduce (teams live in lane bits 3-4)
#pragma unroll
    for (int j = 0; j < 8; ++j) acc[j] += __shfl_xor(acc[j], 8, 64);
#pragma unroll
    for (int j = 0; j < 8; ++j) acc[j] += __shfl_xor(acc[j], 16, 64);
    if (team != 0) return;
    float di = rsqrtf(wsum[i] + 1.0f);
    uint4 hv = h4[(size_t)i * 8 + c];
    float hs[8] = {bf_lo(hv.x), bf_hi(hv.x), bf_lo(hv.y), bf_hi(hv.y),
                   bf_lo(hv.z), bf_hi(hv.z), bf_lo(hv.w), bf_hi(hv.w)};
    float4 b0 = ((const float4*)b)[c * 2];
    float4 b1 = ((const float4*)b)[c * 2 + 1];
    float o[8];
    o[0] = b0.x + di * (hs[0] + acc[0]);
    o[1] = b0.y + di * (hs[1] + acc[1]);
    o[2] = b0.z + di * (hs[2] + acc[2]);
    o[3] = b0.w + di * (hs[3] + acc[3]);
    o[4] = b1.x + di * (hs[4] + acc[4]);
    o[5] = b1.y + di * (hs[5] + acc[5]);
    o[6] = b1.z + di * (hs[6] + acc[6]);
    o[7] = b1.w + di * (hs[7] + acc[7]);
#pragma unroll
    for (int j = 0; j < 8; ++j) o[j] = fmaxf(o[j], 0.f);   // fused relu (out1 only feeds gemm2)
    uint4 ov;
    ov.x = pack2(o[0], o[1]);
    ov.y = pack2(o[2], o[3]);
    ov.z = pack2(o[4], o[5]);
    ov.w = pack2(o[6], o[7]);
    ((uint4*)outb)[(size_t)i * 8 + c] = ov;
}

// Layer 2: 16 lanes/node = 4 teams x 4 ch-lanes, same 2-phase batching; fp32 final out.
__global__ __launch_bounds__(512) void aggregate32(const unsigned* __restrict__ h,
                            const unsigned* __restrict__ row_rc,
                            const u32x2* __restrict__ ew, const float* __restrict__ wsum,
                            const float* __restrict__ b, float* __restrict__ out, int N) {
    int t = threadIdx.x;
    int c = t & 3;                        // uint4 index in row (8 ch per lane)
    int team = (t >> 2) & 3;              // 4 edge teams
    int i = blockIdx.x * 32 + (t >> 4);   // node per 16-lane group
    if (i >= N) return;
    unsigned rc = row_rc[i];
    int beg = (int)(rc & 0x1FFFFFu);
    int len = (int)(rc >> 21);
    int q = len >> 2, r = len & 3;
    int myCnt = q + (team < r ? 1 : 0);
    int myBeg = beg + team * q + (team < r ? team : r);
    const uint4* h4 = (const uint4*)h;
    int m = myCnt < 8 ? myCnt : 8;
    u32x2 ee[8];
#pragma unroll
    for (int j = 0; j < 8; ++j) if (j < m) ee[j] = ew[myBeg + j];
    uint4 vv[8];
#pragma unroll
    for (int j = 0; j < 8; ++j) if (j < m) vv[j] = h4[(size_t)ee[j].x * 4 + c];
    float acc[8];
#pragma unroll
    for (int j = 0; j < 8; ++j) acc[j] = 0.f;
#pragma unroll
    for (int j = 0; j < 8; ++j) if (j < m) {
        float n = __uint_as_float(ee[j].y);
        acc[0] += n * bf_lo(vv[j].x);
        acc[1] += n * bf_hi(vv[j].x);
        acc[2] += n * bf_lo(vv[j].y);
        acc[3] += n * bf_hi(vv[j].y);
        acc[4] += n * bf_lo(vv[j].z);
        acc[5] += n * bf_hi(vv[j].z);
        acc[6] += n * bf_lo(vv[j].w);
        acc[7] += n * bf_hi(vv[j].w);
    }
    for (int k = 8; k < myCnt; ++k) {
        u32x2 e0 = ew[myBeg + k];
        float n0 = __uint_as_float(e0.y);
        uint4 v0 = h4[(size_t)e0.x * 4 + c];
        acc[0] += n0 * bf_lo(v0.x);
        acc[1] += n0 * bf_hi(v0.x);
        acc[2] += n0 * bf_lo(v0.y);
        acc[3] += n0 * bf_hi(v0.y);
        acc[4] += n0 * bf_lo(v0.z);
        acc[5] += n0 * bf_hi(v0.z);
        acc[6] += n0 * bf_lo(v0.w);
        acc[7] += n0 * bf_hi(v0.w);
    }
    // cross-team reduce (teams live in lane bits 2-3)
#pragma unroll
    for (int j = 0; j < 8; ++j) acc[j] += __shfl_xor(acc[j], 4, 64);
#pragma unroll
    for (int j = 0; j < 8; ++j) acc[j] += __shfl_xor(acc[j], 8, 64);
    if (team != 0) return;
    float di = rsqrtf(wsum[i] + 1.0f);
    uint4 hv = h4[(size_t)i * 4 + c];
    float hs[8] = {bf_lo(hv.x), bf_hi(hv.x), bf_lo(hv.y), bf_hi(hv.y),
                   bf_lo(hv.z), bf_hi(hv.z), bf_lo(hv.w), bf_hi(hv.w)};
    float4 b0 = ((const float4*)b)[c * 2];
    float4 b1 = ((const float4*)b)[c * 2 + 1];
    f32x4 o0, o1;
    o0.x = b0.x + di * (hs[0] + acc[0]);
    o0.y = b0.y + di * (hs[1] + acc[1]);
    o0.z = b0.z + di * (hs[2] + acc[2]);
    o0.w = b0.w + di * (hs[3] + acc[3]);
    o1.x = b1.x + di * (hs[4] + acc[4]);
    o1.y = b1.y + di * (hs[5] + acc[5]);
    o1.z = b1.z + di * (hs[6] + acc[6]);
    o1.w = b1.w + di * (hs[7] + acc[7]);
    f32x4* op = (f32x4*)(out + (size_t)i * 32 + c * 8);
    __builtin_nontemporal_store(o0, op);       // final output, never re-read
    __builtin_nontemporal_store(o1, op + 1);
}

extern "C" void kernel_launch(void* const* d_in, const int* in_sizes, int n_in,
                              void* d_out, int out_size, void* d_ws, size_t ws_size,
                              hipStream_t stream) {
    const float* x  = (const float*)d_in[0];
    const int* eidx = (const int*)d_in[1];      // int64 in reference -> int32 on device
    const float* w  = (const float*)d_in[2];
    const float* W1 = (const float*)d_in[3];
    const float* b1 = (const float*)d_in[4];
    const float* W2 = (const float*)d_in[5];
    const float* b2 = (const float*)d_in[6];
    float* out = (float*)d_out;

    const int E = in_sizes[2];
    const int N = in_sizes[0] / 64;
    const int* src = eidx;
    const int* dst = eidx + E;
    const int NB = ceil_div(N, RNODES);          // 391 bins (must be <= 512)

    // workspace carve-up (256B-aligned)
    char* ws = (char*)d_ws;
    size_t off = 0;
    auto alloc = [&](size_t bytes) -> void* {
        void* p = ws + off;
        off = (off + bytes + 255) & ~(size_t)255;
        return p;
    };
    int*      bin_cursor = (int*)alloc((size_t)NB * 4);
    int*      bp         = (int*)alloc((size_t)NB * CAP * 4);  // binned packed (src<<8)|dstoff
    float*    bw         = (float*)alloc((size_t)NB * CAP * 4);
    u32x2*    ew         = (u32x2*)alloc((size_t)NB * CAP * 8);// node-sorted {src, w}
    unsigned* row_rc     = (unsigned*)alloc((size_t)N * 4);    // (cnt<<21)|pos
    float*    wsum       = (float*)alloc((size_t)N * 4);
    unsigned* h1         = (unsigned*)alloc((size_t)N * 32 * 4);  // bf16 N x 64 (dinv-scaled)
    unsigned* out1b      = (unsigned*)alloc((size_t)N * 32 * 4);  // bf16 relu(out1), N x 64
    unsigned* h2         = (unsigned*)alloc((size_t)N * 16 * 4);  // bf16 N x 32 (dinv-scaled)

    (void)hipMemsetAsync(bin_cursor, 0, (size_t)NB * 4, stream);
    bin_scatter<<<ceil_div(E, SC_E), SC_T, 0, stream>>>(src, dst, w, bin_cursor, bp, bw, NB, E);
    build_csr<<<NB, 512, 0, stream>>>(bp, bw, bin_cursor, row_rc, wsum, ew, N);

    // layer 1
    gemm1_mfma<<<ceil_div(N, 64), 256, 0, stream>>>(x, W1, wsum, (unsigned short*)h1, N);
    aggregate64<<<ceil_div(N, 16), 512, 0, stream>>>(h1, row_rc, ew, wsum, b1, out1b, N);

    // layer 2
    gemm2_mfma<<<ceil_div(N, 64), 256, 0, stream>>>((const unsigned short*)out1b, W2, wsum,
                                                    (unsigned short*)h2, N);
    aggregate32<<<ceil_div(N, 32), 512, 0, stream>>>(h2, row_rc, ew, wsum, b2, out, N);
}

// Round 8
// 186.303 us; speedup vs baseline: 1.1809x; 1.1809x over previous
//
#include <hip/hip_runtime.h>

static inline int ceil_div(long long a, long long b) { return (int)((a + b - 1) / b); }

// Node-range binning: bin = dst >> 8 (256 nodes per bin). N <= 131072 assumed (N=100000).
#define RBITS 8
#define RNODES 256
#define CAPB 12
#define CAP 4096   // slots per bin; E/NB ~= 3070, Poisson sigma ~55 -> 4096 is 18-sigma safe

typedef __attribute__((ext_vector_type(8))) short bf16x8;
typedef __attribute__((ext_vector_type(4))) float f32x4;
typedef __attribute__((ext_vector_type(2))) unsigned u32x2;
typedef __attribute__((ext_vector_type(4))) unsigned u32x4;

// bf16 helpers: pack with round-to-nearest-even, unpack via bit ops
__device__ inline unsigned f2bf(float f) {
    unsigned u = __float_as_uint(f);
    return (u + 0x7fffu + ((u >> 16) & 1u)) >> 16;
}
__device__ inline unsigned pack2(float a, float b) { return f2bf(a) | (f2bf(b) << 16); }
__device__ inline float bf2f(unsigned v) { return __uint_as_float(v << 16); }
__device__ inline float bf_lo(unsigned v) { return __uint_as_float(v << 16); }
__device__ inline float bf_hi(unsigned v) { return __uint_as_float(v & 0xffff0000u); }

// ---------------- step 1: partition edges into capped bin regions (LDS staging) ----------------
// bin b owns slots [b*CAP, b*CAP + len_b); bin_cursor[b] ends up = len_b.  (round-6 proven)
#define SC_T 512
#define SC_K 8
#define SC_E (SC_T * SC_K)   // 4096 edges per block
__global__ void bin_scatter(const int* __restrict__ src, const int* __restrict__ dst,
                            const float* __restrict__ w, int* __restrict__ bin_cursor,
                            int* __restrict__ bp, float* __restrict__ bw,
                            int NB, int E) {
    __shared__ int hist[512];
    __shared__ int offs[512];               // inclusive scan of hist
    __shared__ int basex[512];              // global write base per bin
    __shared__ int stage_p[SC_E];
    __shared__ float stage_w[SC_E];
    __shared__ unsigned short stage_b[SC_E]; // bin id per staged slot
    int t = threadIdx.x;
    hist[t] = 0;
    __syncthreads();
    int e0 = blockIdx.x * SC_E;
    int nE = E - e0; if (nE > SC_E) nE = SC_E;

    int myBin[SC_K], myRank[SC_K], myPack[SC_K];
    float myW[SC_K];
#pragma unroll
    for (int k = 0; k < SC_K; ++k) {
        int idx = t + k * SC_T;
        if (idx < nE) {
            int e = e0 + idx;
            int d = dst[e];
            int b = d >> RBITS;
            myBin[k] = b;
            myPack[k] = (src[e] << RBITS) | (d & (RNODES - 1));
            myW[k] = w[e];
            myRank[k] = atomicAdd(&hist[b], 1);
        }
    }
    __syncthreads();
    offs[t] = hist[t];
    __syncthreads();
    for (int d = 1; d < 512; d <<= 1) {
        int a = (t >= d) ? offs[t - d] : 0;
        __syncthreads();
        offs[t] += a;
        __syncthreads();
    }
    if (t < NB && hist[t]) basex[t] = (t << CAPB) + atomicAdd(&bin_cursor[t], hist[t]);
#pragma unroll
    for (int k = 0; k < SC_K; ++k) {
        int idx = t + k * SC_T;
        if (idx < nE) {
            int b = myBin[k];
            int pos = (offs[b] - hist[b]) + myRank[k];
            stage_p[pos] = myPack[k];
            stage_w[pos] = myW[k];
            stage_b[pos] = (unsigned short)b;
        }
    }
    __syncthreads();
    for (int p = t; p < nE; p += SC_T) {
        int b = stage_b[p];
        int g = basex[b] + (p - (offs[b] - hist[b]));
        bp[g] = stage_p[p];
        bw[g] = stage_w[p];
    }
}

// ---------------- step 2: fused degree + CSR scatter (proven round 2/6; wsum output) -------
// row_rc packs (cnt<<21)|pos  (pos < 2^21, cnt < 2^11).
__global__ void build_csr(const int* __restrict__ bp, const float* __restrict__ bw,
                          const int* __restrict__ bin_len,
                          unsigned* __restrict__ row_rc, float* __restrict__ wsum_g,
                          u32x2* __restrict__ ew, int N) {
    __shared__ int bp_s[CAP];
    __shared__ float bw_s[CAP];
    __shared__ int cnt[RNODES];
    __shared__ float wsum[RNODES];
    __shared__ int starts[RNODES];
    __shared__ int cur[RNODES];
    int b = blockIdx.x;
    int t = threadIdx.x;   // 512
    int len = bin_len[b];
    int base = b << CAPB;
    if (t < RNODES) { cnt[t] = 0; wsum[t] = 0.f; }
    __syncthreads();
    for (int e = t; e < len; e += 512) {
        int p = bp[base + e];
        float wv = bw[base + e];
        bp_s[e] = p;
        bw_s[e] = wv;
        atomicAdd(&cnt[p & (RNODES - 1)], 1);
        atomicAdd(&wsum[p & (RNODES - 1)], wv);
    }
    __syncthreads();
    if (t < RNODES) starts[t] = cnt[t];
    __syncthreads();
    for (int d = 1; d < RNODES; d <<= 1) {
        int a = 0;
        if (t < RNODES && t >= d) a = starts[t - d];
        __syncthreads();
        if (t < RNODES) starts[t] += a;
        __syncthreads();
    }
    if (t < RNODES) {
        int s0 = starts[t] - cnt[t];
        cur[t] = s0;
        int node = (b << RBITS) + t;
        if (node < N) {
            row_rc[node] = (unsigned)(base + s0) | ((unsigned)cnt[t] << 21);
            wsum_g[node] = wsum[t];
        }
    }
    __syncthreads();
    for (int e = t; e < len; e += 512) {
        int p = bp_s[e];
        int slot = atomicAdd(&cur[p & (RNODES - 1)], 1);
        u32x2 v;
        v.x = (unsigned)(p >> RBITS);
        v.y = __float_as_uint(bw_s[e]);
        ew[base + slot] = v;
    }
}

// ---------------- MFMA GEMMs (dinv = rsqrt(wsum+1) folded into epilogue; verified r4-r6) -----
__global__ __launch_bounds__(256) void gemm1_mfma(const float* __restrict__ X,
                                                  const float* __restrict__ W,
                                                  const float* __restrict__ wsum,
                                                  unsigned short* __restrict__ H, int N) {
    int lane = threadIdx.x & 63;
    int wv = threadIdx.x >> 6;
    int quad = lane >> 4;
    int col = lane & 15;
    int rb = blockIdx.x * 64 + wv * 16;
    if (rb >= N) return;                      // wave-uniform

    bf16x8 Bh[4][2], Bl[4][2];
#pragma unroll
    for (int nt = 0; nt < 4; ++nt)
#pragma unroll
        for (int kh = 0; kh < 2; ++kh)
#pragma unroll
            for (int j = 0; j < 8; ++j) {
                float wval = W[(kh * 32 + quad * 8 + j) * 64 + nt * 16 + col];
                unsigned hb = f2bf(wval);
                Bh[nt][kh][j] = (short)hb;
                Bl[nt][kh][j] = (short)f2bf(wval - bf2f(hb));
            }

    int arow = rb + col;
    bf16x8 Ah[2], Al[2];
#pragma unroll
    for (int kh = 0; kh < 2; ++kh) {
        float xv[8];
        if (arow < N) {
            const float4* p = (const float4*)(X + (size_t)arow * 64 + kh * 32 + quad * 8);
            float4 f0 = p[0], f1 = p[1];
            xv[0] = f0.x; xv[1] = f0.y; xv[2] = f0.z; xv[3] = f0.w;
            xv[4] = f1.x; xv[5] = f1.y; xv[6] = f1.z; xv[7] = f1.w;
        } else {
#pragma unroll
            for (int j = 0; j < 8; ++j) xv[j] = 0.f;
        }
#pragma unroll
        for (int j = 0; j < 8; ++j) {
            unsigned hb = f2bf(xv[j]);
            Ah[kh][j] = (short)hb;
            Al[kh][j] = (short)f2bf(xv[j] - bf2f(hb));
        }
    }
    f32x4 acc[4] = {{0,0,0,0},{0,0,0,0},{0,0,0,0},{0,0,0,0}};
#pragma unroll
    for (int nt = 0; nt < 4; ++nt)
#pragma unroll
        for (int kh = 0; kh < 2; ++kh) {
            acc[nt] = __builtin_amdgcn_mfma_f32_16x16x32_bf16(Ah[kh], Bh[nt][kh], acc[nt], 0, 0, 0);
            acc[nt] = __builtin_amdgcn_mfma_f32_16x16x32_bf16(Al[kh], Bh[nt][kh], acc[nt], 0, 0, 0);
            acc[nt] = __builtin_amdgcn_mfma_f32_16x16x32_bf16(Ah[kh], Bl[nt][kh], acc[nt], 0, 0, 0);
        }
    float di[4];
#pragma unroll
    for (int r = 0; r < 4; ++r) {
        int row = rb + quad * 4 + r;
        di[r] = (row < N) ? rsqrtf(wsum[row] + 1.0f) : 0.f;
    }
#pragma unroll
    for (int nt = 0; nt < 4; ++nt)
#pragma unroll
        for (int r = 0; r < 4; ++r) {
            int row = rb + quad * 4 + r;
            if (row < N)
                H[(size_t)row * 64 + nt * 16 + col] = (unsigned short)f2bf(di[r] * acc[nt][r]);
        }
}

__global__ __launch_bounds__(256) void gemm2_mfma(const unsigned short* __restrict__ Xb,
                                                  const float* __restrict__ W,
                                                  const float* __restrict__ wsum,
                                                  unsigned short* __restrict__ H, int N) {
    int lane = threadIdx.x & 63;
    int wv = threadIdx.x >> 6;
    int quad = lane >> 4;
    int col = lane & 15;
    int rb = blockIdx.x * 64 + wv * 16;
    if (rb >= N) return;

    bf16x8 Bh[2][2], Bl[2][2];
#pragma unroll
    for (int nt = 0; nt < 2; ++nt)
#pragma unroll
        for (int kh = 0; kh < 2; ++kh)
#pragma unroll
            for (int j = 0; j < 8; ++j) {
                float wval = W[(kh * 32 + quad * 8 + j) * 32 + nt * 16 + col];
                unsigned hb = f2bf(wval);
                Bh[nt][kh][j] = (short)hb;
                Bl[nt][kh][j] = (short)f2bf(wval - bf2f(hb));
            }

    int arow = rb + col;
    bf16x8 A[2];
#pragma unroll
    for (int kh = 0; kh < 2; ++kh) {
        if (arow < N) {
            const bf16x8* p = (const bf16x8*)(Xb + (size_t)arow * 64 + kh * 32 + quad * 8);
            A[kh] = *p;                        // already bf16 — exact
        } else {
            A[kh] = bf16x8{0,0,0,0,0,0,0,0};
        }
    }
    f32x4 acc[2] = {{0,0,0,0},{0,0,0,0}};
#pragma unroll
    for (int nt = 0; nt < 2; ++nt)
#pragma unroll
        for (int kh = 0; kh < 2; ++kh) {
            acc[nt] = __builtin_amdgcn_mfma_f32_16x16x32_bf16(A[kh], Bh[nt][kh], acc[nt], 0, 0, 0);
            acc[nt] = __builtin_amdgcn_mfma_f32_16x16x32_bf16(A[kh], Bl[nt][kh], acc[nt], 0, 0, 0);
        }
    float di[4];
#pragma unroll
    for (int r = 0; r < 4; ++r) {
        int row = rb + quad * 4 + r;
        di[r] = (row < N) ? rsqrtf(wsum[row] + 1.0f) : 0.f;
    }
#pragma unroll
    for (int nt = 0; nt < 2; ++nt)
#pragma unroll
        for (int r = 0; r < 4; ++r) {
            int row = rb + quad * 4 + r;
            if (row < N)
                H[(size_t)row * 32 + nt * 16 + col] = (unsigned short)f2bf(di[r] * acc[nt][r]);
        }
}

// ---------------- aggregation: 32 lanes/node = 4 teams x 8 ch-lanes ----------------
// Fixed 4-wide CLAMPED batch: 4 independent ew loads + 4 independent gathers always in
// flight (index clamped, n=0 past myCnt -> +0.0 terms, bit-identical sums). Tail for cnt>4.
__global__ __launch_bounds__(512) void aggregate64(const unsigned* __restrict__ h,
                            const unsigned* __restrict__ row_rc,
                            const u32x2* __restrict__ ew, const float* __restrict__ wsum,
                            const float* __restrict__ b, unsigned* __restrict__ outb, int N) {
    int t = threadIdx.x;
    int c = t & 7;                        // uint4 index in row (8 ch per lane)
    int team = (t >> 3) & 3;              // 4 edge teams
    int i = blockIdx.x * 16 + (t >> 5);   // node per 32-lane group
    if (i >= N) return;
    unsigned rc = row_rc[i];
    int beg = (int)(rc & 0x1FFFFFu);
    int len = (int)(rc >> 21);
    int q = len >> 2, r = len & 3;
    int myCnt = q + (team < r ? 1 : 0);
    int myBeg = beg + team * q + (team < r ? team : r);
    const uint4* h4 = (const uint4*)h;
    unsigned cl = (unsigned)(N - 1);
    // clamped 4-wide batch (issues even when myCnt<4; clamped dup rows x n=0)
    int m1 = myCnt - 1; if (m1 < 0) m1 = 0; if (m1 > 3) m1 = 3;
    u32x2 e0 = ew[myBeg];
    u32x2 e1 = ew[myBeg + (1 < m1 ? 1 : m1)];
    u32x2 e2 = ew[myBeg + (2 < m1 ? 2 : m1)];
    u32x2 e3 = ew[myBeg + m1];
    float n0 = (0 < myCnt) ? __uint_as_float(e0.y) : 0.f;
    float n1 = (1 < myCnt) ? __uint_as_float(e1.y) : 0.f;
    float n2 = (2 < myCnt) ? __uint_as_float(e2.y) : 0.f;
    float n3 = (3 < myCnt) ? __uint_as_float(e3.y) : 0.f;
    uint4 v0 = h4[(size_t)(e0.x < cl ? e0.x : cl) * 8 + c];
    uint4 v1 = h4[(size_t)(e1.x < cl ? e1.x : cl) * 8 + c];
    uint4 v2 = h4[(size_t)(e2.x < cl ? e2.x : cl) * 8 + c];
    uint4 v3 = h4[(size_t)(e3.x < cl ? e3.x : cl) * 8 + c];
    float acc[8];
    acc[0] = n0 * bf_lo(v0.x) + n1 * bf_lo(v1.x) + n2 * bf_lo(v2.x) + n3 * bf_lo(v3.x);
    acc[1] = n0 * bf_hi(v0.x) + n1 * bf_hi(v1.x) + n2 * bf_hi(v2.x) + n3 * bf_hi(v3.x);
    acc[2] = n0 * bf_lo(v0.y) + n1 * bf_lo(v1.y) + n2 * bf_lo(v2.y) + n3 * bf_lo(v3.y);
    acc[3] = n0 * bf_hi(v0.y) + n1 * bf_hi(v1.y) + n2 * bf_hi(v2.y) + n3 * bf_hi(v3.y);
    acc[4] = n0 * bf_lo(v0.z) + n1 * bf_lo(v1.z) + n2 * bf_lo(v2.z) + n3 * bf_lo(v3.z);
    acc[5] = n0 * bf_hi(v0.z) + n1 * bf_hi(v1.z) + n2 * bf_hi(v2.z) + n3 * bf_hi(v3.z);
    acc[6] = n0 * bf_lo(v0.w) + n1 * bf_lo(v1.w) + n2 * bf_lo(v2.w) + n3 * bf_lo(v3.w);
    acc[7] = n0 * bf_hi(v0.w) + n1 * bf_hi(v1.w) + n2 * bf_hi(v2.w) + n3 * bf_hi(v3.w);
    for (int k = 4; k < myCnt; ++k) {     // tail (team cnt > 4: deg > 16, P~0.1)
        u32x2 ek = ew[myBeg + k];
        float nk = __uint_as_float(ek.y);
        uint4 vk = h4[(size_t)ek.x * 8 + c];
        acc[0] += nk * bf_lo(vk.x);
        acc[1] += nk * bf_hi(vk.x);
        acc[2] += nk * bf_lo(vk.y);
        acc[3] += nk * bf_hi(vk.y);
        acc[4] += nk * bf_lo(vk.z);
        acc[5] += nk * bf_hi(vk.z);
        acc[6] += nk * bf_lo(vk.w);
        acc[7] += nk * bf_hi(vk.w);
    }
    // cross-team reduce (teams live in lane bits 3-4)
#pragma unroll
    for (int j = 0; j < 8; ++j) acc[j] += __shfl_xor(acc[j], 8, 64);
#pragma unroll
    for (int j = 0; j < 8; ++j) acc[j] += __shfl_xor(acc[j], 16, 64);
    if (team != 0) return;
    float di = rsqrtf(wsum[i] + 1.0f);
    uint4 hv = h4[(size_t)i * 8 + c];
    float hs[8] = {bf_lo(hv.x), bf_hi(hv.x), bf_lo(hv.y), bf_hi(hv.y),
                   bf_lo(hv.z), bf_hi(hv.z), bf_lo(hv.w), bf_hi(hv.w)};
    float4 b0 = ((const float4*)b)[c * 2];
    float4 b1 = ((const float4*)b)[c * 2 + 1];
    float o[8];
    o[0] = b0.x + di * (hs[0] + acc[0]);
    o[1] = b0.y + di * (hs[1] + acc[1]);
    o[2] = b0.z + di * (hs[2] + acc[2]);
    o[3] = b0.w + di * (hs[3] + acc[3]);
    o[4] = b1.x + di * (hs[4] + acc[4]);
    o[5] = b1.y + di * (hs[5] + acc[5]);
    o[6] = b1.z + di * (hs[6] + acc[6]);
    o[7] = b1.w + di * (hs[7] + acc[7]);
#pragma unroll
    for (int j = 0; j < 8; ++j) o[j] = fmaxf(o[j], 0.f);   // fused relu (out1 only feeds gemm2)
    uint4 ov;
    ov.x = pack2(o[0], o[1]);
    ov.y = pack2(o[2], o[3]);
    ov.z = pack2(o[4], o[5]);
    ov.w = pack2(o[6], o[7]);
    ((uint4*)outb)[(size_t)i * 8 + c] = ov;
}

// Layer 2: 16 lanes/node = 4 teams x 4 ch-lanes, same clamped batch; fp32 final out.
__global__ __launch_bounds__(512) void aggregate32(const unsigned* __restrict__ h,
                            const unsigned* __restrict__ row_rc,
                            const u32x2* __restrict__ ew, const float* __restrict__ wsum,
                            const float* __restrict__ b, float* __restrict__ out, int N) {
    int t = threadIdx.x;
    int c = t & 3;                        // uint4 index in row (8 ch per lane)
    int team = (t >> 2) & 3;              // 4 edge teams
    int i = blockIdx.x * 32 + (t >> 4);   // node per 16-lane group
    if (i >= N) return;
    unsigned rc = row_rc[i];
    int beg = (int)(rc & 0x1FFFFFu);
    int len = (int)(rc >> 21);
    int q = len >> 2, r = len & 3;
    int myCnt = q + (team < r ? 1 : 0);
    int myBeg = beg + team * q + (team < r ? team : r);
    const uint4* h4 = (const uint4*)h;
    unsigned cl = (unsigned)(N - 1);
    int m1 = myCnt - 1; if (m1 < 0) m1 = 0; if (m1 > 3) m1 = 3;
    u32x2 e0 = ew[myBeg];
    u32x2 e1 = ew[myBeg + (1 < m1 ? 1 : m1)];
    u32x2 e2 = ew[myBeg + (2 < m1 ? 2 : m1)];
    u32x2 e3 = ew[myBeg + m1];
    float n0 = (0 < myCnt) ? __uint_as_float(e0.y) : 0.f;
    float n1 = (1 < myCnt) ? __uint_as_float(e1.y) : 0.f;
    float n2 = (2 < myCnt) ? __uint_as_float(e2.y) : 0.f;
    float n3 = (3 < myCnt) ? __uint_as_float(e3.y) : 0.f;
    uint4 v0 = h4[(size_t)(e0.x < cl ? e0.x : cl) * 4 + c];
    uint4 v1 = h4[(size_t)(e1.x < cl ? e1.x : cl) * 4 + c];
    uint4 v2 = h4[(size_t)(e2.x < cl ? e2.x : cl) * 4 + c];
    uint4 v3 = h4[(size_t)(e3.x < cl ? e3.x : cl) * 4 + c];
    float acc[8];
    acc[0] = n0 * bf_lo(v0.x) + n1 * bf_lo(v1.x) + n2 * bf_lo(v2.x) + n3 * bf_lo(v3.x);
    acc[1] = n0 * bf_hi(v0.x) + n1 * bf_hi(v1.x) + n2 * bf_hi(v2.x) + n3 * bf_hi(v3.x);
    acc[2] = n0 * bf_lo(v0.y) + n1 * bf_lo(v1.y) + n2 * bf_lo(v2.y) + n3 * bf_lo(v3.y);
    acc[3] = n0 * bf_hi(v0.y) + n1 * bf_hi(v1.y) + n2 * bf_hi(v2.y) + n3 * bf_hi(v3.y);
    acc[4] = n0 * bf_lo(v0.z) + n1 * bf_lo(v1.z) + n2 * bf_lo(v2.z) + n3 * bf_lo(v3.z);
    acc[5] = n0 * bf_hi(v0.z) + n1 * bf_hi(v1.z) + n2 * bf_hi(v2.z) + n3 * bf_hi(v3.z);
    acc[6] = n0 * bf_lo(v0.w) + n1 * bf_lo(v1.w) + n2 * bf_lo(v2.w) + n3 * bf_lo(v3.w);
    acc[7] = n0 * bf_hi(v0.w) + n1 * bf_hi(v1.w) + n2 * bf_hi(v2.w) + n3 * bf_hi(v3.w);
    for (int k = 4; k < myCnt; ++k) {
        u32x2 ek = ew[myBeg + k];
        float nk = __uint_as_float(ek.y);
        uint4 vk = h4[(size_t)ek.x * 4 + c];
        acc[0] += nk * bf_lo(vk.x);
        acc[1] += nk * bf_hi(vk.x);
        acc[2] += nk * bf_lo(vk.y);
        acc[3] += nk * bf_hi(vk.y);
        acc[4] += nk * bf_lo(vk.z);
        acc[5] += nk * bf_hi(vk.z);
        acc[6] += nk * bf_lo(vk.w);
        acc[7] += nk * bf_hi(vk.w);
    }
    // cross-team reduce (teams live in lane bits 2-3)
#pragma unroll
    for (int j = 0; j < 8; ++j) acc[j] += __shfl_xor(acc[j], 4, 64);
#pragma unroll
    for (int j = 0; j < 8; ++j) acc[j] += __shfl_xor(acc[j], 8, 64);
    if (team != 0) return;
    float di = rsqrtf(wsum[i] + 1.0f);
    uint4 hv = h4[(size_t)i * 4 + c];
    float hs[8] = {bf_lo(hv.x), bf_hi(hv.x), bf_lo(hv.y), bf_hi(hv.y),
                   bf_lo(hv.z), bf_hi(hv.z), bf_lo(hv.w), bf_hi(hv.w)};
    float4 b0 = ((const float4*)b)[c * 2];
    float4 b1 = ((const float4*)b)[c * 2 + 1];
    f32x4 o0, o1;
    o0.x = b0.x + di * (hs[0] + acc[0]);
    o0.y = b0.y + di * (hs[1] + acc[1]);
    o0.z = b0.z + di * (hs[2] + acc[2]);
    o0.w = b0.w + di * (hs[3] + acc[3]);
    o1.x = b1.x + di * (hs[4] + acc[4]);
    o1.y = b1.y + di * (hs[5] + acc[5]);
    o1.z = b1.z + di * (hs[6] + acc[6]);
    o1.w = b1.w + di * (hs[7] + acc[7]);
    f32x4* op = (f32x4*)(out + (size_t)i * 32 + c * 8);
    __builtin_nontemporal_store(o0, op);       // final output, never re-read
    __builtin_nontemporal_store(o1, op + 1);
}

extern "C" void kernel_launch(void* const* d_in, const int* in_sizes, int n_in,
                              void* d_out, int out_size, void* d_ws, size_t ws_size,
                              hipStream_t stream) {
    const float* x  = (const float*)d_in[0];
    const int* eidx = (const int*)d_in[1];      // int64 in reference -> int32 on device
    const float* w  = (const float*)d_in[2];
    const float* W1 = (const float*)d_in[3];
    const float* b1 = (const float*)d_in[4];
    const float* W2 = (const float*)d_in[5];
    const float* b2 = (const float*)d_in[6];
    float* out = (float*)d_out;

    const int E = in_sizes[2];
    const int N = in_sizes[0] / 64;
    const int* src = eidx;
    const int* dst = eidx + E;
    const int NB = ceil_div(N, RNODES);          // 391 bins (must be <= 512)

    // workspace carve-up (256B-aligned)
    char* ws = (char*)d_ws;
    size_t off = 0;
    auto alloc = [&](size_t bytes) -> void* {
        void* p = ws + off;
        off = (off + bytes + 255) & ~(size_t)255;
        return p;
    };
    int*      bin_cursor = (int*)alloc((size_t)NB * 4);
    int*      bp         = (int*)alloc((size_t)NB * CAP * 4);  // binned packed (src<<8)|dstoff
    float*    bw         = (float*)alloc((size_t)NB * CAP * 4);
    u32x2*    ew         = (u32x2*)alloc((size_t)NB * CAP * 8 + 1024); // +pad for clamped reads
    unsigned* row_rc     = (unsigned*)alloc((size_t)N * 4);    // (cnt<<21)|pos
    float*    wsum       = (float*)alloc((size_t)N * 4);
    unsigned* h1         = (unsigned*)alloc((size_t)N * 32 * 4);  // bf16 N x 64 (dinv-scaled)
    unsigned* out1b      = (unsigned*)alloc((size_t)N * 32 * 4);  // bf16 relu(out1), N x 64
    unsigned* h2         = (unsigned*)alloc((size_t)N * 16 * 4);  // bf16 N x 32 (dinv-scaled)

    (void)hipMemsetAsync(bin_cursor, 0, (size_t)NB * 4, stream);
    bin_scatter<<<ceil_div(E, SC_E), SC_T, 0, stream>>>(src, dst, w, bin_cursor, bp, bw, NB, E);
    build_csr<<<NB, 512, 0, stream>>>(bp, bw, bin_cursor, row_rc, wsum, ew, N);

    // layer 1
    gemm1_mfma<<<ceil_div(N, 64), 256, 0, stream>>>(x, W1, wsum, (unsigned short*)h1, N);
    aggregate64<<<ceil_div(N, 16), 512, 0, stream>>>(h1, row_rc, ew, wsum, b1, out1b, N);

    // layer 2
    gemm2_mfma<<<ceil_div(N, 64), 256, 0, stream>>>((const unsigned short*)out1b, W2, wsum,
                                                    (unsigned short*)h2, N);
    aggregate32<<<ceil_div(N, 32), 512, 0, stream>>>(h2, row_rc, ew, wsum, b2, out, N);
}